// Round 20
// baseline (72.479 us; speedup 1.0000x reference)
//
#include <hip/hip_runtime.h>

#define T_TOTAL 200000
#define NL 49
#define NP 50
#define NB 20
#define TB 32                        // timesteps per block
#define THREADS 256                  // 4 waves; wave owns 8 timesteps
#define WPB 4
#define TPW 8
#define NBLK (T_TOTAL / TB)          // 6250
#define POSN 1656                    // union per comp: max(1617 angles, 1652 pos) pad16

typedef float floatx4 __attribute__((ext_vector_type(4)));   // native vec for NT store

// Block-contiguous position layout [33][50] unioned with the angle staging
// buffer -> LDS 19.9KB = 8 blocks/CU; each wave computes only its 8 rows
// (wave 3 adds halo row 32): 33 chains/block vs 36. NT output stores.
__global__ __launch_bounds__(THREADS, 6) void bbf_fused(
    const float* __restrict__ lines,
    const float* __restrict__ rootsx,
    const float* __restrict__ rootsy,
    const float* __restrict__ rootsz,
    const float* __restrict__ ax,
    const float* __restrict__ ay,
    const float* __restrict__ az,
    const float* __restrict__ tarx,
    const float* __restrict__ tary,
    const float* __restrict__ w,
    float* __restrict__ outx,
    float* __restrict__ outy,
    float* __restrict__ outz,
    double* __restrict__ partials)   // [NBLK][2]
{
    // union: [0,1617) staged angles -> [0,1652) positions (33 rows x 50)
    __shared__ __align__(16) float bx[POSN];
    __shared__ __align__(16) float by[POSN];
    __shared__ __align__(16) float bz[POSN];
    __shared__ double redL[WPB], redR[WPB];

    const int tid  = threadIdx.x;
    const int lane = tid & 63;
    const int wv   = tid >> 6;
    const int t0   = blockIdx.x * TB;
    const int nrows = min(TB + 1, T_TOTAL - t0);   // 33 (last block 32)
    const int nload = nrows * NL;

    const bool isNode = (lane < NP);
    const bool isLimb = (lane >= 1 && lane < NP);
    const int  li = isLimb ? (lane - 1) : 0;

    const float Lv = isLimb ? expf(lines[li % NB]) : 0.f;

    // ancestor jump table (pointer jumping 1,2,4; depth<=5; root-clamped)
    const int a1 = isLimb ? ((lane - 1) >> 1) : 0;
    const int a2 = (a1 > 0) ? ((a1 - 1) >> 1) : 0;
    const int a3 = (a2 > 0) ? ((a2 - 1) >> 1) : 0;
    const int a4 = (a3 > 0) ? ((a3 - 1) >> 1) : 0;

    // ---- Phase 0: cooperative float4 staging of angles -> LDS ----
    {
        const float4* ax4 = (const float4*)(ax + (size_t)t0 * NL);  // 16B aligned
        const float4* ay4 = (const float4*)(ay + (size_t)t0 * NL);
        const float4* az4 = (const float4*)(az + (size_t)t0 * NL);
        const int nv4 = nload >> 2;              // 404 (last block 392)
        for (int k4 = tid; k4 < nv4; k4 += THREADS) {
            ((float4*)bx)[k4] = ax4[k4];
            ((float4*)by)[k4] = ay4[k4];
            ((float4*)bz)[k4] = az4[k4];
        }
        for (int k = (nload & ~3) + tid; k < nload; k += THREADS) {  // <=1 tail
            bx[k] = ax[(size_t)t0 * NL + k];
            by[k] = ay[(size_t)t0 * NL + k];
            bz[k] = az[(size_t)t0 * NL + k];
        }
    }
    __syncthreads();

    // ---- Phase A: wave reads its angle scalars to registers ----
    const int rb = __builtin_amdgcn_readfirstlane(wv * TPW);   // wave's first row
    const int kmax = (wv == WPB - 1) ? 9 : 8;    // wave 3 also does halo row 32
    float arx[9], ary[9], arz[9];
#pragma unroll
    for (int k = 0; k < 9; ++k) {
        if (k < kmax) {
            const int r = min(rb + k, nrows - 1);   // clamp (last block halo)
            const int o = r * NL + li;              // consecutive -> conflict-free
            arx[k] = bx[o];
            ary[k] = by[o];
            arz[k] = bz[o];
        }
    }
    // roots (wave-uniform -> s_loads)
    float rxv[9], ryv[9], rzv[9];
#pragma unroll
    for (int k = 0; k < 9; ++k) {
        if (k < kmax) {
            const int t = min(t0 + rb + k, T_TOTAL - 1);
            rxv[k] = rootsx[t]; ryv[k] = rootsy[t]; rzv[k] = rootsz[t];
        }
    }
    __syncthreads();   // all angle reads done -> safe to overwrite buffer

    // ---- Phase A2: chains -> block-contiguous positions [row][node] ----
#pragma unroll
    for (int k = 0; k < 9; ++k) {
        if (k < kmax) {
            const float x = arx[k], y = ary[k], z = arz[k];
            const float n = sqrtf(x * x + y * y + z * z) + 1e-10f;
            const float s = Lv / n;                  // 0 for non-limb lanes
            float dx = x * s, dy = y * s, dz = z * s;
            dx += __shfl(dx, a1); dy += __shfl(dy, a1); dz += __shfl(dz, a1);
            dx += __shfl(dx, a2); dy += __shfl(dy, a2); dz += __shfl(dz, a2);
            dx += __shfl(dx, a4); dy += __shfl(dy, a4); dz += __shfl(dz, a4);
            if (isNode) {
                const int o = (rb + k) * NP + lane;
                bx[o] = dx + rxv[k];
                by[o] = dy + ryv[k];
                bz[o] = dz + rzv[k];
            }
        }
    }
    __syncthreads();   // positions complete across waves

    // ---- Phase B: float4 loss/reg2 + NT output stores (own 8 rows) ----
    const size_t gb = (size_t)(t0 + rb) * NP;    // x200B -> 16B aligned
    const float4* tx4 = (const float4*)(tarx + gb);
    const float4* ty4 = (const float4*)(tary + gb);
    const float4* qw4 = (const float4*)(w + gb);
    floatx4* ox4 = (floatx4*)(outx + gb);
    floatx4* oy4 = (floatx4*)(outy + gb);
    floatx4* oz4 = (floatx4*)(outz + gb);
    const float* xw = bx + rb * NP;
    const float* yw = by + rb * NP;
    const float* zw = bz + rb * NP;

    float lossAcc = 0.f, regAcc = 0.f;
#pragma unroll
    for (int it = 0; it < 2; ++it) {
        const int c = lane + it * 64;            // 100 float4 groups per wave
        if (c < (TPW * NP) / 4) {
            const int j = c << 2;
            const floatx4 X = *(const floatx4*)&xw[j];
            const floatx4 Y = *(const floatx4*)&yw[j];
            const floatx4 Z = *(const floatx4*)&zw[j];
            __builtin_nontemporal_store(X, &ox4[c]);   // bypass L2/L3
            __builtin_nontemporal_store(Y, &oy4[c]);
            __builtin_nontemporal_store(Z, &oz4[c]);
            const float4 TX = tx4[c];
            const float4 TY = ty4[c];
            const float4 WV = qw4[c];
            const float4 XA = *(const float4*)&xw[j + 48];
            const float4 XB = *(const float4*)&xw[j + 52];
            const float4 YA = *(const float4*)&yw[j + 48];
            const float4 YB = *(const float4*)&yw[j + 52];
            const float4 ZA = *(const float4*)&zw[j + 48];
            const float4 ZB = *(const float4*)&zw[j + 52];
            const float xv[4] = {X.x, X.y, X.z, X.w};
            const float yv[4] = {Y.x, Y.y, Y.z, Y.w};
            const float zv[4] = {Z.x, Z.y, Z.z, Z.w};
            const float tx[4] = {TX.x, TX.y, TX.z, TX.w};
            const float ty[4] = {TY.x, TY.y, TY.z, TY.w};
            const float qv[4] = {WV.x, WV.y, WV.z, WV.w};
            const float xn[4] = {XA.z, XA.w, XB.x, XB.y};   // floats j+50..j+53
            const float yn[4] = {YA.z, YA.w, YB.x, YB.y};
            const float zn[4] = {ZA.z, ZA.w, ZB.x, ZB.y};
#pragma unroll
            for (int e = 0; e < 4; ++e) {
                const float ex = xv[e] - tx[e];
                const float ey = yv[e] - ty[e];
                lossAcc += qv[e] * (ex * ex + ey * ey);
                const float d1 = xv[e] - xn[e];
                const float d2 = yv[e] - yn[e];
                const float d3 = zv[e] - zn[e];
                regAcc += d1 * d1 + d2 * d2 + d3 * d3;
            }
        }
    }

    // wave reduce -> cross-wave LDS -> per-block partial slot
    for (int off = 32; off > 0; off >>= 1) {
        lossAcc += __shfl_down(lossAcc, off);
        regAcc  += __shfl_down(regAcc, off);
    }
    if (lane == 0) { redL[wv] = (double)lossAcc; redR[wv] = (double)regAcc; }
    __syncthreads();
    if (tid == 0) {
        double l = 0.0, r = 0.0;
        for (int i = 0; i < WPB; ++i) { l += redL[i]; r += redR[i]; }
        partials[2 * (size_t)blockIdx.x]     = l;
        partials[2 * (size_t)blockIdx.x + 1] = r;
    }
}

__global__ __launch_bounds__(1024) void bbf_finalize(
    const float* __restrict__ lines,
    const double* __restrict__ partials,
    float* __restrict__ out_total)
{
    __shared__ double rl[16], rr[16];
    const int tid = threadIdx.x;
    double l = 0.0, r = 0.0;
    for (int i = tid; i < NBLK; i += 1024) {
        l += partials[2 * (size_t)i];
        r += partials[2 * (size_t)i + 1];
    }
    for (int off = 32; off > 0; off >>= 1) {
        l += __shfl_down(l, off);
        r += __shfl_down(r, off);
    }
    const int wid = tid >> 6;
    if ((tid & 63) == 0) { rl[wid] = l; rr[wid] = r; }
    __syncthreads();
    if (tid == 0) {
        double L = 0.0, R = 0.0;
        for (int i = 0; i < 16; ++i) { L += rl[i]; R += rr[i]; }
        double reg1 = 0.0;
        for (int i = 0; i < NB; ++i) reg1 += (double)expf(lines[i]);
        const double loss = L / ((double)T_TOTAL * (double)NP);
        const double reg2 = R / ((double)(T_TOTAL - 1) * (double)NP);
        *out_total = (float)(loss + 0.001 * reg1 + 0.1 * reg2);
    }
}

extern "C" void kernel_launch(void* const* d_in, const int* in_sizes, int n_in,
                              void* d_out, int out_size, void* d_ws, size_t ws_size,
                              hipStream_t stream) {
    const float* lines  = (const float*)d_in[0];
    const float* rootsx = (const float*)d_in[1];
    const float* rootsy = (const float*)d_in[2];
    const float* rootsz = (const float*)d_in[3];
    const float* ax     = (const float*)d_in[4];
    const float* ay     = (const float*)d_in[5];
    const float* az     = (const float*)d_in[6];
    const float* tarx   = (const float*)d_in[7];
    const float* tary   = (const float*)d_in[8];
    const float* w      = (const float*)d_in[9];

    float* out = (float*)d_out;
    const size_t plane = (size_t)T_TOTAL * NP;
    float* outx = out;
    float* outy = out + plane;
    float* outz = out + 2 * plane;
    float* out_total = out + 3 * plane;

    double* partials = (double*)d_ws;   // NBLK*2 doubles = 100 KB

    bbf_fused<<<NBLK, THREADS, 0, stream>>>(
        lines, rootsx, rootsy, rootsz, ax, ay, az, tarx, tary, w,
        outx, outy, outz, partials);
    bbf_finalize<<<1, 1024, 0, stream>>>(lines, partials, out_total);
}

// Round 21
// 69.875 us; speedup vs baseline: 1.0373x; 1.0373x over previous
//
#include <hip/hip_runtime.h>

#define T_TOTAL 200000
#define NL 49
#define NP 50
#define NB 20
#define TB 32                        // timesteps per block
#define THREADS 256                  // 4 waves; wave owns 8 timesteps
#define WPB 4
#define TPW 8
#define NBLK (T_TOTAL / TB)          // 6250
#define RSTRIDE 456                  // per-wave position region (450 + pad)

typedef float floatx4 __attribute__((ext_vector_type(4)));   // native vec for NT store

// Best measured configuration (R19, 70.0 us):
// - angles staged block-cooperatively (float4) into LDS
// - per-wave register shuffle-prefix chains (incl. halo row) -> positions in
//   the wave's PRIVATE region of the reused LDS buffer (no 3rd barrier)
// - float4 loss/reg2 pass with j+48/j+52 neighbor reads
// - NON-TEMPORAL output stores (keep outputs out of L2/L3; ~6us win)
__global__ __launch_bounds__(THREADS, 6) void bbf_fused(
    const float* __restrict__ lines,
    const float* __restrict__ rootsx,
    const float* __restrict__ rootsy,
    const float* __restrict__ rootsz,
    const float* __restrict__ ax,
    const float* __restrict__ ay,
    const float* __restrict__ az,
    const float* __restrict__ tarx,
    const float* __restrict__ tary,
    const float* __restrict__ w,
    float* __restrict__ outx,
    float* __restrict__ outy,
    float* __restrict__ outz,
    double* __restrict__ partials)   // [NBLK][2]
{
    // union buffer: [0,1617) angles (33 rows x 49)  ->  4 x 456 positions
    __shared__ __align__(16) float bx[WPB * RSTRIDE];
    __shared__ __align__(16) float by[WPB * RSTRIDE];
    __shared__ __align__(16) float bz[WPB * RSTRIDE];
    __shared__ double redL[WPB], redR[WPB];

    const int tid  = threadIdx.x;
    const int lane = tid & 63;
    const int wv   = tid >> 6;
    const int t0   = blockIdx.x * TB;
    const int nrows = min(TB + 1, T_TOTAL - t0);   // 33 (last block 32)
    const int nload = nrows * NL;

    const bool isNode = (lane < NP);
    const bool isLimb = (lane >= 1 && lane < NP);
    const int  li = isLimb ? (lane - 1) : 0;

    const float Lv = isLimb ? expf(lines[li % NB]) : 0.f;

    // ancestor jump table (pointer jumping 1,2,4; depth<=5; root-clamped)
    const int a1 = isLimb ? ((lane - 1) >> 1) : 0;
    const int a2 = (a1 > 0) ? ((a1 - 1) >> 1) : 0;
    const int a3 = (a2 > 0) ? ((a2 - 1) >> 1) : 0;
    const int a4 = (a3 > 0) ? ((a3 - 1) >> 1) : 0;

    // ---- Phase 0: cooperative float4 staging of angles -> LDS ----
    {
        const float4* ax4 = (const float4*)(ax + (size_t)t0 * NL);  // 16B aligned
        const float4* ay4 = (const float4*)(ay + (size_t)t0 * NL);
        const float4* az4 = (const float4*)(az + (size_t)t0 * NL);
        const int nv4 = nload >> 2;              // 404 (last block 392)
        for (int k4 = tid; k4 < nv4; k4 += THREADS) {
            ((float4*)bx)[k4] = ax4[k4];
            ((float4*)by)[k4] = ay4[k4];
            ((float4*)bz)[k4] = az4[k4];
        }
        for (int k = (nload & ~3) + tid; k < nload; k += THREADS) {  // <=1 tail
            bx[k] = ax[(size_t)t0 * NL + k];
            by[k] = ay[(size_t)t0 * NL + k];
            bz[k] = az[(size_t)t0 * NL + k];
        }
    }
    __syncthreads();

    // ---- Phase A: wave reads its 27 lane=limb angle scalars to registers ----
    const int rb = __builtin_amdgcn_readfirstlane(wv * TPW);   // wave's first row
    float arx[9], ary[9], arz[9];
#pragma unroll
    for (int k = 0; k < 9; ++k) {
        const int r = min(rb + k, nrows - 1);    // halo clamp (last block wave 3)
        const int o = r * NL + li;               // consecutive -> conflict-free
        arx[k] = bx[o];
        ary[k] = by[o];
        arz[k] = bz[o];
    }
    // roots (wave-uniform -> s_loads)
    float rxv[9], ryv[9], rzv[9];
#pragma unroll
    for (int k = 0; k < 9; ++k) {
        const int t = min(t0 + rb + k, T_TOTAL - 1);
        rxv[k] = rootsx[t]; ryv[k] = rootsy[t]; rzv[k] = rootsz[t];
    }
    __syncthreads();   // all angle reads done -> safe to overwrite buffer

    // ---- Phase A2: 9 register prefix chains -> own LDS position region ----
    float* xw = bx + wv * RSTRIDE;
    float* yw = by + wv * RSTRIDE;
    float* zw = bz + wv * RSTRIDE;
#pragma unroll
    for (int k = 0; k < 9; ++k) {
        const float x = arx[k], y = ary[k], z = arz[k];
        const float n = sqrtf(x * x + y * y + z * z) + 1e-10f;
        const float s = Lv / n;                  // 0 for non-limb lanes
        float dx = x * s, dy = y * s, dz = z * s;
        dx += __shfl(dx, a1); dy += __shfl(dy, a1); dz += __shfl(dz, a1);
        dx += __shfl(dx, a2); dy += __shfl(dy, a2); dz += __shfl(dz, a2);
        dx += __shfl(dx, a4); dy += __shfl(dy, a4); dz += __shfl(dz, a4);
        if (isNode) {
            xw[k * NP + lane] = dx + rxv[k];
            yw[k * NP + lane] = dy + ryv[k];
            zw[k * NP + lane] = dz + rzv[k];
        }
    }

    // ---- Phase B: float4 loss/reg2 + NON-TEMPORAL output stores ----
    const size_t gb = (size_t)(t0 + rb) * NP;    // x200B -> 16B aligned
    const float4* tx4 = (const float4*)(tarx + gb);
    const float4* ty4 = (const float4*)(tary + gb);
    const float4* qw4 = (const float4*)(w + gb);
    floatx4* ox4 = (floatx4*)(outx + gb);
    floatx4* oy4 = (floatx4*)(outy + gb);
    floatx4* oz4 = (floatx4*)(outz + gb);

    float lossAcc = 0.f, regAcc = 0.f;
#pragma unroll
    for (int it = 0; it < 2; ++it) {
        const int c = lane + it * 64;            // 100 float4 groups per wave
        if (c < (TPW * NP) / 4) {
            const int j = c << 2;
            const floatx4 X = *(const floatx4*)&xw[j];
            const floatx4 Y = *(const floatx4*)&yw[j];
            const floatx4 Z = *(const floatx4*)&zw[j];
            __builtin_nontemporal_store(X, &ox4[c]);   // bypass L2/L3
            __builtin_nontemporal_store(Y, &oy4[c]);
            __builtin_nontemporal_store(Z, &oz4[c]);
            const float4 TX = tx4[c];
            const float4 TY = ty4[c];
            const float4 WV = qw4[c];
            const float4 XA = *(const float4*)&xw[j + 48];
            const float4 XB = *(const float4*)&xw[j + 52];
            const float4 YA = *(const float4*)&yw[j + 48];
            const float4 YB = *(const float4*)&yw[j + 52];
            const float4 ZA = *(const float4*)&zw[j + 48];
            const float4 ZB = *(const float4*)&zw[j + 52];
            const float xv[4] = {X.x, X.y, X.z, X.w};
            const float yv[4] = {Y.x, Y.y, Y.z, Y.w};
            const float zv[4] = {Z.x, Z.y, Z.z, Z.w};
            const float tx[4] = {TX.x, TX.y, TX.z, TX.w};
            const float ty[4] = {TY.x, TY.y, TY.z, TY.w};
            const float qv[4] = {WV.x, WV.y, WV.z, WV.w};
            const float xn[4] = {XA.z, XA.w, XB.x, XB.y};   // floats j+50..j+53
            const float yn[4] = {YA.z, YA.w, YB.x, YB.y};
            const float zn[4] = {ZA.z, ZA.w, ZB.x, ZB.y};
#pragma unroll
            for (int e = 0; e < 4; ++e) {
                const float ex = xv[e] - tx[e];
                const float ey = yv[e] - ty[e];
                lossAcc += qv[e] * (ex * ex + ey * ey);
                const float d1 = xv[e] - xn[e];
                const float d2 = yv[e] - yn[e];
                const float d3 = zv[e] - zn[e];
                regAcc += d1 * d1 + d2 * d2 + d3 * d3;
            }
        }
    }

    // wave reduce -> cross-wave LDS -> per-block partial slot
    for (int off = 32; off > 0; off >>= 1) {
        lossAcc += __shfl_down(lossAcc, off);
        regAcc  += __shfl_down(regAcc, off);
    }
    if (lane == 0) { redL[wv] = (double)lossAcc; redR[wv] = (double)regAcc; }
    __syncthreads();
    if (tid == 0) {
        double l = 0.0, r = 0.0;
        for (int i = 0; i < WPB; ++i) { l += redL[i]; r += redR[i]; }
        partials[2 * (size_t)blockIdx.x]     = l;
        partials[2 * (size_t)blockIdx.x + 1] = r;
    }
}

__global__ __launch_bounds__(1024) void bbf_finalize(
    const float* __restrict__ lines,
    const double* __restrict__ partials,
    float* __restrict__ out_total)
{
    __shared__ double rl[16], rr[16];
    const int tid = threadIdx.x;
    double l = 0.0, r = 0.0;
    for (int i = tid; i < NBLK; i += 1024) {
        l += partials[2 * (size_t)i];
        r += partials[2 * (size_t)i + 1];
    }
    for (int off = 32; off > 0; off >>= 1) {
        l += __shfl_down(l, off);
        r += __shfl_down(r, off);
    }
    const int wid = tid >> 6;
    if ((tid & 63) == 0) { rl[wid] = l; rr[wid] = r; }
    __syncthreads();
    if (tid == 0) {
        double L = 0.0, R = 0.0;
        for (int i = 0; i < 16; ++i) { L += rl[i]; R += rr[i]; }
        double reg1 = 0.0;
        for (int i = 0; i < NB; ++i) reg1 += (double)expf(lines[i]);
        const double loss = L / ((double)T_TOTAL * (double)NP);
        const double reg2 = R / ((double)(T_TOTAL - 1) * (double)NP);
        *out_total = (float)(loss + 0.001 * reg1 + 0.1 * reg2);
    }
}

extern "C" void kernel_launch(void* const* d_in, const int* in_sizes, int n_in,
                              void* d_out, int out_size, void* d_ws, size_t ws_size,
                              hipStream_t stream) {
    const float* lines  = (const float*)d_in[0];
    const float* rootsx = (const float*)d_in[1];
    const float* rootsy = (const float*)d_in[2];
    const float* rootsz = (const float*)d_in[3];
    const float* ax     = (const float*)d_in[4];
    const float* ay     = (const float*)d_in[5];
    const float* az     = (const float*)d_in[6];
    const float* tarx   = (const float*)d_in[7];
    const float* tary   = (const float*)d_in[8];
    const float* w      = (const float*)d_in[9];

    float* out = (float*)d_out;
    const size_t plane = (size_t)T_TOTAL * NP;
    float* outx = out;
    float* outy = out + plane;
    float* outz = out + 2 * plane;
    float* out_total = out + 3 * plane;

    double* partials = (double*)d_ws;   // NBLK*2 doubles = 100 KB

    bbf_fused<<<NBLK, THREADS, 0, stream>>>(
        lines, rootsx, rootsy, rootsz, ax, ay, az, tarx, tary, w,
        outx, outy, outz, partials);
    bbf_finalize<<<1, 1024, 0, stream>>>(lines, partials, out_total);
}